// Round 1
// baseline (152.604 us; speedup 1.0000x reference)
//
#include <hip/hip_runtime.h>

#define NN 8192
#define FF 256
#define MM 128
#define HSLOTS 262144   // power of 2, 2x edge count
#define NTILES 2080     // 64*65/2 upper-tri 128x128 tiles

typedef __attribute__((ext_vector_type(8))) short bf16x8;
typedef __attribute__((ext_vector_type(4))) float f32x4;

// ws layout (bytes):
// [0, 16K): partial sums, 3 arrays x 64 slots, 64B apart + done-counter
// [16K, +2MB): z bf16 [NN][MM]
// [.., +1MB): dedup hash set (u32 keys, 0 = empty; zeroed in prep_w)
// [.., +64KB): WmuT bf16 [MM][FF]   (transposed, K contiguous)
// [.., +64KB): WsgT bf16 [MM][FF]
#define P_KL    0
#define P_EDGE  (64 * 16)
#define P_SP    (128 * 16)
#define P_CNT   3072          // float index; u32 done-counter (zeroed by prep_w)
#define Z_OFF   16384
#define Z_BYTES (NN * MM * 2)
#define HASH_OFF (Z_OFF + Z_BYTES)
#define WT_OFF  (HASH_OFF + HSLOTS * 4)
#define WT_BYTES (MM * FF * 2)

__device__ __forceinline__ float wave_reduce(float v) {
    #pragma unroll
    for (int off = 32; off > 0; off >>= 1) v += __shfl_down(v, off);
    return v;
}
__device__ __forceinline__ unsigned short f2bf(float f) {
    unsigned int u = __float_as_uint(f);
    u += 0x7fffu + ((u >> 16) & 1u);   // round to nearest even
    return (unsigned short)(u >> 16);
}
__device__ __forceinline__ int4 pack8(float4 a, float4 b) {
    int4 p;
    p.x = (int)f2bf(a.x) | ((int)f2bf(a.y) << 16);
    p.y = (int)f2bf(a.z) | ((int)f2bf(a.w) << 16);
    p.z = (int)f2bf(b.x) | ((int)f2bf(b.y) << 16);
    p.w = (int)f2bf(b.z) | ((int)f2bf(b.w) << 16);
    return p;
}

// ---- prep: W transpose->bf16, zero partials+counter, zero hash table -----
__global__ __launch_bounds__(256)
void prep_w(const float* __restrict__ Wmu, const float* __restrict__ Wsg,
            unsigned short* __restrict__ WmuT, unsigned short* __restrict__ WsgT,
            float* __restrict__ part, unsigned int* __restrict__ ht) {
    const int t = blockIdx.x * 256 + threadIdx.x;   // 0..32767
    const int n = t >> 8, f = t & 255;
    WmuT[t] = f2bf(Wmu[f * MM + n]);
    WsgT[t] = f2bf(Wsg[f * MM + n]);
    if (t < 4096) part[t] = 0.f;          // 16 KB of partial slots + P_CNT
    uint4 z4 = {0u, 0u, 0u, 0u};
    ((uint4*)ht)[t * 2]     = z4;         // 32768*2 uint4 = 262144 words
    ((uint4*)ht)[t * 2 + 1] = z4;
}

// ---- encoder: MFMA GEMMs, W-fragments direct from global, 1 barrier ------
#define XP_I4 33   // int4 pitch per x row (32 data + 1 pad)
#define XP_S  264

__global__ __launch_bounds__(256)
void encoder_mfma(const float* __restrict__ x, const float* __restrict__ eps,
                  const unsigned short* __restrict__ WmuT,
                  const unsigned short* __restrict__ WsgT,
                  const float* __restrict__ bmu, const float* __restrict__ bsg,
                  unsigned short* __restrict__ zb, float* __restrict__ part) {
    __shared__ int4 ax[16 * XP_I4];   // 8.4 KB: 16 x-rows, K=256 bf16
    __shared__ float red[4];
    const int tid = threadIdx.x;
    const int wid = tid >> 6, lane = tid & 63;
    const int l15 = lane & 15, quad = lane >> 4;
    const int row0 = blockIdx.x * 16;

    {   // stage 16 rows x 256 cols of x as bf16 (coalesced float4 pairs)
        const int r = tid >> 4, ch = tid & 15;
        const float4* g0 = (const float4*)(x + (size_t)(row0 + r) * FF + ch * 8);
        const float4* g1 = (const float4*)(x + (size_t)(row0 + r) * FF + (ch + 16) * 8);
        ax[r * XP_I4 + ch]      = pack8(g0[0], g0[1]);
        ax[r * XP_I4 + ch + 16] = pack8(g1[0], g1[1]);
    }
    __syncthreads();

    const short* sax = (const short*)ax;
    const int4* wtm = (const int4*)WmuT;   // row n = 32 int4 (K=256)
    const int4* wts = (const int4*)WsgT;

    f32x4 zero4 = {0.f, 0.f, 0.f, 0.f};
    f32x4 accm[2], accl[2];
    accm[0] = accm[1] = accl[0] = accl[1] = zero4;

    #pragma unroll
    for (int ks = 0; ks < 8; ++ks) {       // K = 8 x 32
        const bf16x8 a = *(const bf16x8*)&sax[l15 * XP_S + ks * 32 + quad * 8];
        #pragma unroll
        for (int j = 0; j < 2; ++j) {
            const int n = wid * 32 + j * 16 + l15;
            const bf16x8 bmf = *(const bf16x8*)&wtm[n * 32 + ks * 4 + quad];
            const bf16x8 bsf = *(const bf16x8*)&wts[n * 32 + ks * 4 + quad];
            accm[j] = __builtin_amdgcn_mfma_f32_16x16x32_bf16(a, bmf, accm[j], 0, 0, 0);
            accl[j] = __builtin_amdgcn_mfma_f32_16x16x32_bf16(a, bsf, accl[j], 0, 0, 0);
        }
    }

    // epilogue: C map col=lane&15, row=quad*4+reg [m89]
    float klp = 0.f;
    #pragma unroll
    for (int j = 0; j < 2; ++j) {
        const int col = wid * 32 + j * 16 + l15;
        const float bm = bmu[col], bs = bsg[col];
        #pragma unroll
        for (int r = 0; r < 4; ++r) {
            const int row = row0 + quad * 4 + r;
            const float mu = accm[j][r] + bm;
            const float ls = accl[j][r] + bs;
            const float sg = __expf(ls);
            const float zz = fmaf(sg, eps[(size_t)row * MM + col], mu);
            zb[(size_t)row * MM + col] = f2bf(zz);
            klp += 0.5f * (sg * sg + mu * mu - 1.f) - ls;
        }
    }

    klp = wave_reduce(klp);
    if (lane == 0) red[wid] = klp;
    __syncthreads();
    if (tid == 0)
        atomicAdd(&part[P_KL + (blockIdx.x & 63) * 16],
                  red[0] + red[1] + red[2] + red[3]);
}

// ---- fused: edge blocks [0,NE) + triangular tile blocks [NE,NE+2080) -----
// edge role: dedup hash, sum exact s_ij over unique pairs (bf16 z)
// tile role: MFMA bf16 upper-tri z@z^T + fused softplus
// last finished block performs the final combine (no separate launch)
__device__ __forceinline__ float dotpair(unsigned int a, unsigned int b) {
    const float al = __uint_as_float(a << 16);
    const float ah = __uint_as_float(a & 0xffff0000u);
    const float bl = __uint_as_float(b << 16);
    const float bh = __uint_as_float(b & 0xffff0000u);
    return fmaf(al, bl, ah * bh);
}

__global__ __launch_bounds__(256, 3)
void fused_kernel(const int* __restrict__ ei, int E, int NE,
                  const unsigned short* __restrict__ zb,
                  unsigned int* __restrict__ ht,
                  float* __restrict__ part, float* __restrict__ out) {
    // XOR-swizzled unpadded LDS: tile = 128 rows x 8 int4 (BK=64), chunk ch of
    // row r stored at slot ch^(r&7). 2 tiles x 16 KB = 32 KB (3 blocks/CU).
    __shared__ int4 la[128 * 8];
    __shared__ int4 lb[128 * 8];
    __shared__ int lastflag;

    const int tid = threadIdx.x;
    const int bid = blockIdx.x;

    if (bid < NE) {
        // ================= edge role (latency-bound, dispatched first) ====
        const int e = bid * 256 + tid;
        float contrib = 0.f;
        if (e < E) {
            const int i = ei[e];
            const int j = ei[E + e];
            if (i != j) {
                const int a = min(i, j), b = max(i, j);
                const unsigned int key = (unsigned int)a * NN + b;  // >=1, <2^26
                unsigned int slot = (key * 2654435761u) & (HSLOTS - 1);
                bool first = false;
                for (;;) {
                    const unsigned int old = atomicCAS(&ht[slot], 0u, key);
                    if (old == 0u) { first = true; break; }
                    if (old == key) break;
                    slot = (slot + 1) & (HSLOTS - 1);
                }
                if (first) {
                    const uint4* za = (const uint4*)(zb + (size_t)a * MM);
                    const uint4* zc = (const uint4*)(zb + (size_t)b * MM);
                    float s = 0.f;
                    #pragma unroll
                    for (int q = 0; q < MM / 8; ++q) {
                        const uint4 ua = za[q], ub = zc[q];
                        s += dotpair(ua.x, ub.x) + dotpair(ua.y, ub.y)
                           + dotpair(ua.z, ub.z) + dotpair(ua.w, ub.w);
                    }
                    contrib = s;
                }
            }
        }
        contrib = wave_reduce(contrib);
        if ((tid & 63) == 0)
            atomicAdd(&part[P_EDGE + (bid & 63) * 16], contrib);
    } else {
        // ================= tile role ======================================
        // triangular map: t -> (bi<=bj) over 64x64 tile grid
        const int t = bid - NE;
        int bi = (int)((129.0f - sqrtf(16641.0f - 8.0f * (float)t)) * 0.5f);
        bi = min(max(bi, 0), 63);
        while ((bi * (129 - bi)) / 2 > t) --bi;                 // off(bi) > t
        while (((bi + 1) * (128 - bi)) / 2 <= t) ++bi;          // off(bi+1) <= t
        const int bj = bi + (t - (bi * (129 - bi)) / 2);

        const int wid = tid >> 6, lane = tid & 63;
        const int wm = wid >> 1, wn = wid & 1;
        const int l15 = lane & 15, quad = lane >> 4;
        const int xk = l15 & 7;                 // xor key for fragment reads

        const int4* ga = (const int4*)(zb + (size_t)bi * 128 * MM);
        const int4* gb = (const int4*)(zb + (size_t)bj * 128 * MM);

        f32x4 zero4 = {0.f, 0.f, 0.f, 0.f};
        f32x4 acc[4][4];
        #pragma unroll
        for (int i = 0; i < 4; ++i)
            #pragma unroll
            for (int j = 0; j < 4; ++j) acc[i][j] = zero4;

        const short* sa = (const short*)la;
        const short* sb = (const short*)lb;

        #pragma unroll
        for (int kc = 0; kc < 2; ++kc) {        // K halves of 64
            if (kc) __syncthreads();
            #pragma unroll
            for (int i = 0; i < 4; ++i) {       // stage both tiles, swizzled
                const int c = tid + i * 256;    // 0..1023
                const int row = c >> 3, ch = c & 7;
                const int sl = ch ^ (row & 7);
                la[row * 8 + sl] = ga[row * 16 + kc * 8 + ch];
                lb[row * 8 + sl] = gb[row * 16 + kc * 8 + ch];
            }
            __syncthreads();
            #pragma unroll
            for (int ks = 0; ks < 2; ++ks) {    // two k=32 MFMA steps
                const int kq = ks * 4 + quad;   // chunk index 0..7 (int4 units)
                bf16x8 af[4], bfr[4];
                #pragma unroll
                for (int t2 = 0; t2 < 4; ++t2) {
                    const int ar = wm * 64 + t2 * 16 + l15;
                    af[t2]  = *(const bf16x8*)&sa[ar * 64 + ((kq ^ xk) * 8)];
                    const int br = wn * 64 + t2 * 16 + l15;
                    bfr[t2] = *(const bf16x8*)&sb[br * 64 + ((kq ^ xk) * 8)];
                }
                #pragma unroll
                for (int i = 0; i < 4; ++i)
                    #pragma unroll
                    for (int j = 0; j < 4; ++j)
                        acc[i][j] = __builtin_amdgcn_mfma_f32_16x16x32_bf16(
                            af[i], bfr[j], acc[i][j], 0, 0, 0);
            }
        }

        // softplus(v) ~= max(v,0) + e - e^2/2, e=exp(-|v|); err <= e^3/3
        float tsum = 0.f;
        if (bi != bj) {
            #pragma unroll
            for (int i = 0; i < 4; ++i)
                #pragma unroll
                for (int j = 0; j < 4; ++j)
                    #pragma unroll
                    for (int r = 0; r < 4; ++r) {
                        const float v = acc[i][j][r];
                        const float e = __expf(-fabsf(v));
                        tsum += fmaxf(v, 0.f) + e * fmaf(e, -0.5f, 1.f);
                    }
        } else {
            const int rbase = wm * 64 + quad * 4;
            const int cbase = wn * 64 + l15;
            #pragma unroll
            for (int i = 0; i < 4; ++i)
                #pragma unroll
                for (int j = 0; j < 4; ++j)
                    #pragma unroll
                    for (int r = 0; r < 4; ++r)
                        if (cbase + j * 16 > rbase + i * 16 + r) {
                            const float v = acc[i][j][r];
                            const float e = __expf(-fabsf(v));
                            tsum += fmaxf(v, 0.f) + e * fmaf(e, -0.5f, 1.f);
                        }
        }

        tsum = wave_reduce(tsum);
        if (lane == 0)
            atomicAdd(&part[P_SP + ((bi * 64 + bj + wid * 16) & 63) * 16], tsum);
    }

    // ---- last-block-done combine (replaces combine_kernel launch) --------
    __syncthreads();
    if (tid == 0) {
        __threadfence();   // make this block's partials visible device-wide
        const unsigned int old =
            atomicAdd(reinterpret_cast<unsigned int*>(part) + P_CNT, 1u);
        lastflag = (old == gridDim.x - 1) ? 1 : 0;
    }
    __syncthreads();
    if (lastflag && tid < 64) {
        __threadfence();   // acquire: all other blocks' partials visible
        float v = __hip_atomic_load(&part[P_SP + tid * 16],
                                    __ATOMIC_RELAXED, __HIP_MEMORY_SCOPE_AGENT)
                - __hip_atomic_load(&part[P_EDGE + tid * 16],
                                    __ATOMIC_RELAXED, __HIP_MEMORY_SCOPE_AGENT)
                + 0.001f * __hip_atomic_load(&part[P_KL + tid * 16],
                                    __ATOMIC_RELAXED, __HIP_MEMORY_SCOPE_AGENT);
        v = wave_reduce(v);
        if (tid == 0) out[0] = v;
    }
}

extern "C" void kernel_launch(void* const* d_in, const int* in_sizes, int n_in,
                              void* d_out, int out_size, void* d_ws, size_t ws_size,
                              hipStream_t stream) {
    const float* x   = (const float*)d_in[0];
    const int* ei    = (const int*)d_in[1];     // int32 on device
    const float* eps = (const float*)d_in[2];
    const float* Wmu = (const float*)d_in[3];
    const float* bmu = (const float*)d_in[4];
    const float* Wsg = (const float*)d_in[5];
    const float* bsg = (const float*)d_in[6];
    float* out = (float*)d_out;
    char* ws = (char*)d_ws;

    float* part = (float*)ws;
    unsigned short* zb = (unsigned short*)(ws + Z_OFF);
    unsigned int* ht = (unsigned int*)(ws + HASH_OFF);
    unsigned short* WmuT = (unsigned short*)(ws + WT_OFF);
    unsigned short* WsgT = (unsigned short*)(ws + WT_OFF + WT_BYTES);
    const int E = in_sizes[1] / 2;
    const int NE = (E + 255) / 256;

    prep_w<<<128, 256, 0, stream>>>(Wmu, Wsg, WmuT, WsgT, part, ht);
    encoder_mfma<<<NN / 16, 256, 0, stream>>>(x, eps, WmuT, WsgT, bmu, bsg, zb, part);
    fused_kernel<<<NE + NTILES, 256, 0, stream>>>(ei, E, NE, zb, ht, part, out);
}

// Round 2
// 114.031 us; speedup vs baseline: 1.3383x; 1.3383x over previous
//
#include <hip/hip_runtime.h>

#define NN 8192
#define FF 256
#define MM 128
#define HSLOTS 262144   // power of 2, 2x edge count
#define NTILES 2080     // 64*65/2 upper-tri 128x128 tiles

typedef __attribute__((ext_vector_type(8))) short bf16x8;
typedef __attribute__((ext_vector_type(4))) float f32x4;

// ws layout (bytes):
// [0, 16K): partial sums, 3 arrays x 64 slots, 64B apart
// [16K, +2MB): z bf16 [NN][MM]
// [.., +1MB): dedup hash set (u32 keys, 0 = empty; zeroed in prep_w)
// [.., +64KB): WmuT bf16 [MM][FF]   (transposed, K contiguous)
// [.., +64KB): WsgT bf16 [MM][FF]
#define P_KL    0
#define P_EDGE  (64 * 16)
#define P_SP    (128 * 16)
#define Z_OFF   16384
#define Z_BYTES (NN * MM * 2)
#define HASH_OFF (Z_OFF + Z_BYTES)
#define WT_OFF  (HASH_OFF + HSLOTS * 4)
#define WT_BYTES (MM * FF * 2)

__device__ __forceinline__ float wave_reduce(float v) {
    #pragma unroll
    for (int off = 32; off > 0; off >>= 1) v += __shfl_down(v, off);
    return v;
}
__device__ __forceinline__ unsigned short f2bf(float f) {
    unsigned int u = __float_as_uint(f);
    u += 0x7fffu + ((u >> 16) & 1u);   // round to nearest even
    return (unsigned short)(u >> 16);
}
__device__ __forceinline__ int4 pack8(float4 a, float4 b) {
    int4 p;
    p.x = (int)f2bf(a.x) | ((int)f2bf(a.y) << 16);
    p.y = (int)f2bf(a.z) | ((int)f2bf(a.w) << 16);
    p.z = (int)f2bf(b.x) | ((int)f2bf(b.y) << 16);
    p.w = (int)f2bf(b.z) | ((int)f2bf(b.w) << 16);
    return p;
}

// ---- prep: W transpose->bf16, zero partials, zero hash table -------------
__global__ __launch_bounds__(256)
void prep_w(const float* __restrict__ Wmu, const float* __restrict__ Wsg,
            unsigned short* __restrict__ WmuT, unsigned short* __restrict__ WsgT,
            float* __restrict__ part, unsigned int* __restrict__ ht) {
    const int t = blockIdx.x * 256 + threadIdx.x;   // 0..32767
    const int n = t >> 8, f = t & 255;
    WmuT[t] = f2bf(Wmu[f * MM + n]);
    WsgT[t] = f2bf(Wsg[f * MM + n]);
    if (t < 4096) part[t] = 0.f;          // 16 KB of partial slots
    uint4 z4 = {0u, 0u, 0u, 0u};
    ((uint4*)ht)[t * 2]     = z4;         // 32768*2 uint4 = 262144 words
    ((uint4*)ht)[t * 2 + 1] = z4;
}

// ---- encoder: MFMA GEMMs, W-fragments direct from global, 1 barrier ------
#define XP_I4 33   // int4 pitch per x row (32 data + 1 pad)
#define XP_S  264

__global__ __launch_bounds__(256)
void encoder_mfma(const float* __restrict__ x, const float* __restrict__ eps,
                  const unsigned short* __restrict__ WmuT,
                  const unsigned short* __restrict__ WsgT,
                  const float* __restrict__ bmu, const float* __restrict__ bsg,
                  unsigned short* __restrict__ zb, float* __restrict__ part) {
    __shared__ int4 ax[16 * XP_I4];   // 8.4 KB: 16 x-rows, K=256 bf16
    __shared__ float red[4];
    const int tid = threadIdx.x;
    const int wid = tid >> 6, lane = tid & 63;
    const int l15 = lane & 15, quad = lane >> 4;
    const int row0 = blockIdx.x * 16;

    {   // stage 16 rows x 256 cols of x as bf16 (coalesced float4 pairs)
        const int r = tid >> 4, ch = tid & 15;
        const float4* g0 = (const float4*)(x + (size_t)(row0 + r) * FF + ch * 8);
        const float4* g1 = (const float4*)(x + (size_t)(row0 + r) * FF + (ch + 16) * 8);
        ax[r * XP_I4 + ch]      = pack8(g0[0], g0[1]);
        ax[r * XP_I4 + ch + 16] = pack8(g1[0], g1[1]);
    }
    __syncthreads();

    const short* sax = (const short*)ax;
    const int4* wtm = (const int4*)WmuT;   // row n = 32 int4 (K=256)
    const int4* wts = (const int4*)WsgT;

    f32x4 zero4 = {0.f, 0.f, 0.f, 0.f};
    f32x4 accm[2], accl[2];
    accm[0] = accm[1] = accl[0] = accl[1] = zero4;

    #pragma unroll
    for (int ks = 0; ks < 8; ++ks) {       // K = 8 x 32
        const bf16x8 a = *(const bf16x8*)&sax[l15 * XP_S + ks * 32 + quad * 8];
        #pragma unroll
        for (int j = 0; j < 2; ++j) {
            const int n = wid * 32 + j * 16 + l15;
            const bf16x8 bmf = *(const bf16x8*)&wtm[n * 32 + ks * 4 + quad];
            const bf16x8 bsf = *(const bf16x8*)&wts[n * 32 + ks * 4 + quad];
            accm[j] = __builtin_amdgcn_mfma_f32_16x16x32_bf16(a, bmf, accm[j], 0, 0, 0);
            accl[j] = __builtin_amdgcn_mfma_f32_16x16x32_bf16(a, bsf, accl[j], 0, 0, 0);
        }
    }

    // epilogue: C map col=lane&15, row=quad*4+reg [m89]
    float klp = 0.f;
    #pragma unroll
    for (int j = 0; j < 2; ++j) {
        const int col = wid * 32 + j * 16 + l15;
        const float bm = bmu[col], bs = bsg[col];
        #pragma unroll
        for (int r = 0; r < 4; ++r) {
            const int row = row0 + quad * 4 + r;
            const float mu = accm[j][r] + bm;
            const float ls = accl[j][r] + bs;
            const float sg = __expf(ls);
            const float zz = fmaf(sg, eps[(size_t)row * MM + col], mu);
            zb[(size_t)row * MM + col] = f2bf(zz);
            klp += 0.5f * (sg * sg + mu * mu - 1.f) - ls;
        }
    }

    klp = wave_reduce(klp);
    if (lane == 0) red[wid] = klp;
    __syncthreads();
    if (tid == 0)
        atomicAdd(&part[P_KL + (blockIdx.x & 63) * 16],
                  red[0] + red[1] + red[2] + red[3]);
}

// ---- helpers for edge tail ----------------------------------------------
__device__ __forceinline__ float dotpair(unsigned int a, unsigned int b) {
    const float al = __uint_as_float(a << 16);
    const float ah = __uint_as_float(a & 0xffff0000u);
    const float bl = __uint_as_float(b << 16);
    const float bh = __uint_as_float(b & 0xffff0000u);
    return fmaf(al, bl, ah * bh);
}

// ---- tile+edge: triangular-mapped MFMA z@z^T tiles; blocks [0,NE) also ---
// process 256 edges each AFTER their tile (uniform entry: no role branch,
// no per-block fence). Edge latency hides under later blocks' tile compute.
__global__ __launch_bounds__(256, 3)
void tile_edge_kernel(const unsigned short* __restrict__ zb,
                      const int* __restrict__ ei, int E, int NE,
                      unsigned int* __restrict__ ht,
                      float* __restrict__ part) {
    // XOR-swizzled unpadded LDS: tile = 128 rows x 8 int4 (BK=64), chunk ch of
    // row r stored at slot ch^(r&7). 2 tiles x 16 KB = 32 KB.
    __shared__ int4 la[128 * 8];
    __shared__ int4 lb[128 * 8];

    const int tid = threadIdx.x;
    const int bid = blockIdx.x;

    // triangular map: bid -> (bi<=bj) over 64x64 tile grid
    // off(bi) = bi*(129-bi)/2 ; row bi holds 64-bi tiles
    int bi = (int)((129.0f - sqrtf(16641.0f - 8.0f * (float)bid)) * 0.5f);
    bi = min(max(bi, 0), 63);
    while ((bi * (129 - bi)) / 2 > bid) --bi;
    while (((bi + 1) * (128 - bi)) / 2 <= bid) ++bi;
    const int bj = bi + (bid - (bi * (129 - bi)) / 2);

    const int wid = tid >> 6, lane = tid & 63;
    const int wm = wid >> 1, wn = wid & 1;
    const int l15 = lane & 15, quad = lane >> 4;
    const int xk = l15 & 7;                 // xor key for fragment reads

    const int4* ga = (const int4*)(zb + (size_t)bi * 128 * MM);
    const int4* gb = (const int4*)(zb + (size_t)bj * 128 * MM);

    f32x4 zero4 = {0.f, 0.f, 0.f, 0.f};
    f32x4 acc[4][4];
    #pragma unroll
    for (int i = 0; i < 4; ++i)
        #pragma unroll
        for (int j = 0; j < 4; ++j) acc[i][j] = zero4;

    const short* sa = (const short*)la;
    const short* sb = (const short*)lb;

    #pragma unroll
    for (int kc = 0; kc < 2; ++kc) {        // K halves of 64
        if (kc) __syncthreads();
        #pragma unroll
        for (int i = 0; i < 4; ++i) {       // stage both tiles, swizzled
            const int c = tid + i * 256;    // 0..1023
            const int row = c >> 3, ch = c & 7;
            const int sl = ch ^ (row & 7);
            la[row * 8 + sl] = ga[row * 16 + kc * 8 + ch];
            lb[row * 8 + sl] = gb[row * 16 + kc * 8 + ch];
        }
        __syncthreads();
        #pragma unroll
        for (int ks = 0; ks < 2; ++ks) {    // two k=32 MFMA steps
            const int kq = ks * 4 + quad;   // chunk index 0..7 (int4 units)
            bf16x8 af[4], bfr[4];
            #pragma unroll
            for (int t2 = 0; t2 < 4; ++t2) {
                const int ar = wm * 64 + t2 * 16 + l15;
                af[t2]  = *(const bf16x8*)&sa[ar * 64 + ((kq ^ xk) * 8)];
                const int br = wn * 64 + t2 * 16 + l15;
                bfr[t2] = *(const bf16x8*)&sb[br * 64 + ((kq ^ xk) * 8)];
            }
            #pragma unroll
            for (int i = 0; i < 4; ++i)
                #pragma unroll
                for (int j = 0; j < 4; ++j)
                    acc[i][j] = __builtin_amdgcn_mfma_f32_16x16x32_bf16(
                        af[i], bfr[j], acc[i][j], 0, 0, 0);
        }
    }

    // softplus(v) ~= max(v,0) + e - e^2/2, e=exp(-|v|); err <= e^3/3,
    // summed bound ~1e5 << 1.2e7 threshold
    float tsum = 0.f;
    if (bi != bj) {
        #pragma unroll
        for (int i = 0; i < 4; ++i)
            #pragma unroll
            for (int j = 0; j < 4; ++j)
                #pragma unroll
                for (int r = 0; r < 4; ++r) {
                    const float v = acc[i][j][r];
                    const float e = __expf(-fabsf(v));
                    tsum += fmaxf(v, 0.f) + e * fmaf(e, -0.5f, 1.f);
                }
    } else {
        const int rbase = wm * 64 + quad * 4;
        const int cbase = wn * 64 + l15;
        #pragma unroll
        for (int i = 0; i < 4; ++i)
            #pragma unroll
            for (int j = 0; j < 4; ++j)
                #pragma unroll
                for (int r = 0; r < 4; ++r)
                    if (cbase + j * 16 > rbase + i * 16 + r) {
                        const float v = acc[i][j][r];
                        const float e = __expf(-fabsf(v));
                        tsum += fmaxf(v, 0.f) + e * fmaf(e, -0.5f, 1.f);
                    }
    }

    tsum = wave_reduce(tsum);
    if (lane == 0)   // per-wave atomic: no barrier needed
        atomicAdd(&part[P_SP + ((bi * 64 + bj + wid * 16) & 63) * 16], tsum);

    // ---- edge tail: first NE blocks (dispatched earliest) do 256 edges ---
    if (bid < NE) {
        const int e = bid * 256 + tid;
        float contrib = 0.f;
        if (e < E) {
            const int i = ei[e];
            const int j = ei[E + e];
            if (i != j) {
                const int a = min(i, j), b = max(i, j);
                const unsigned int key = (unsigned int)a * NN + b;  // >=1, <2^26
                unsigned int slot = (key * 2654435761u) & (HSLOTS - 1);
                bool first = false;
                for (;;) {
                    const unsigned int old = atomicCAS(&ht[slot], 0u, key);
                    if (old == 0u) { first = true; break; }
                    if (old == key) break;
                    slot = (slot + 1) & (HSLOTS - 1);
                }
                if (first) {
                    const uint4* za = (const uint4*)(zb + (size_t)a * MM);
                    const uint4* zc = (const uint4*)(zb + (size_t)b * MM);
                    float s = 0.f;
                    #pragma unroll
                    for (int q = 0; q < MM / 8; ++q) {
                        const uint4 ua = za[q], ub = zc[q];
                        s += dotpair(ua.x, ub.x) + dotpair(ua.y, ub.y)
                           + dotpair(ua.z, ub.z) + dotpair(ua.w, ub.w);
                    }
                    contrib = s;
                }
            }
        }
        contrib = wave_reduce(contrib);
        if ((tid & 63) == 0)
            atomicAdd(&part[P_EDGE + (bid & 63) * 16], contrib);
    }
}

// ---- final combine: sum 3 x 64 partial slots ----------------------------
__global__ void combine_kernel(const float* __restrict__ part,
                               float* __restrict__ out) {
    const int t = threadIdx.x;   // 64 threads
    float v = part[P_SP + t * 16] - part[P_EDGE + t * 16]
            + 0.001f * part[P_KL + t * 16];
    v = wave_reduce(v);
    if (t == 0) out[0] = v;
}

extern "C" void kernel_launch(void* const* d_in, const int* in_sizes, int n_in,
                              void* d_out, int out_size, void* d_ws, size_t ws_size,
                              hipStream_t stream) {
    const float* x   = (const float*)d_in[0];
    const int* ei    = (const int*)d_in[1];     // int32 on device
    const float* eps = (const float*)d_in[2];
    const float* Wmu = (const float*)d_in[3];
    const float* bmu = (const float*)d_in[4];
    const float* Wsg = (const float*)d_in[5];
    const float* bsg = (const float*)d_in[6];
    float* out = (float*)d_out;
    char* ws = (char*)d_ws;

    float* part = (float*)ws;
    unsigned short* zb = (unsigned short*)(ws + Z_OFF);
    unsigned int* ht = (unsigned int*)(ws + HASH_OFF);
    unsigned short* WmuT = (unsigned short*)(ws + WT_OFF);
    unsigned short* WsgT = (unsigned short*)(ws + WT_OFF + WT_BYTES);
    const int E = in_sizes[1] / 2;
    const int NE = (E + 255) / 256;             // 512

    prep_w<<<128, 256, 0, stream>>>(Wmu, Wsg, WmuT, WsgT, part, ht);
    encoder_mfma<<<NN / 16, 256, 0, stream>>>(x, eps, WmuT, WsgT, bmu, bsg, zb, part);
    tile_edge_kernel<<<NTILES, 256, 0, stream>>>(zb, ei, E, NE, ht, part);
    combine_kernel<<<1, 64, 0, stream>>>(part, out);
}